// Round 4
// baseline (252.200 us; speedup 1.0000x reference)
//
#include <hip/hip_runtime.h>
#include <math.h>

#define N_ROWS 400      // bs*Q
#define M_ROWS 80       // = 5*16, exact
#define K_CLS  134
#define PN     12544    // = 392*32 = 256*49
#define PFULL  65536    // 256*256
#define NSUB   25       // 400/16 n-subtiles
#define TSTEPS 392      // PN/32 MFMA k-steps
#define KSPLIT 56
#define TPB    7        // TSTEPS/KSPLIT

typedef __attribute__((ext_vector_type(4))) float  f32x4;
typedef __attribute__((ext_vector_type(8))) __bf16 bf16x8;

__device__ __forceinline__ float wave_reduce_sum(float v) {
#pragma unroll
    for (int off = 32; off > 0; off >>= 1) v += __shfl_down(v, off, 64);
    return v;
}

// --- softmax stats over (400,134) ---
__global__ void softmax_stats_kernel(const float* __restrict__ logits,
                                     float* __restrict__ rowmax,
                                     float* __restrict__ rowsum) {
    int n = blockIdx.x;
    const float* row = logits + n * K_CLS;
    int l = threadIdx.x;  // 64 threads = 1 wave
    float mx = -1e30f;
    for (int k = l; k < K_CLS; k += 64) mx = fmaxf(mx, row[k]);
#pragma unroll
    for (int off = 32; off > 0; off >>= 1) mx = fmaxf(mx, __shfl_down(mx, off, 64));
    mx = __shfl(mx, 0, 64);
    float se = 0.f;
    for (int k = l; k < K_CLS; k += 64) se += expf(row[k] - mx);
    se = wave_reduce_sum(se);
    if (l == 0) { rowmax[n] = mx; rowsum[n] = se; }
}

// --- gather x at sampled points -> packed bf16 Xb, Sb (row-major 400 x PN),
//     plus exact fp32 spsum/ssum per row. One block per row. ---
__global__ __launch_bounds__(512) void gather_x_kernel(
        const float* __restrict__ pred_masks, const int* __restrict__ point_idx,
        __bf16* __restrict__ Xb, __bf16* __restrict__ Sb,
        float* __restrict__ spsum, float* __restrict__ ssum) {
    int n = blockIdx.x;
    const float* row = pred_masks + (size_t)n * PFULL;
    __bf16* xrow = Xb + (size_t)n * PN;
    __bf16* srow = Sb + (size_t)n * PN;
    float ssp = 0.f, sss = 0.f;
#pragma unroll 4
    for (int p = threadIdx.x; p < PN; p += 512) {
        int idx = point_idx[p];
        float x  = row[idx];
        float ax = fabsf(x);
        float e  = __expf(-ax);
        float inv = __builtin_amdgcn_rcpf(1.0f + e);
        float sig = (x >= 0.f) ? inv : e * inv;
        float sp  = fmaxf(x, 0.f) + __logf(1.0f + e);
        xrow[p] = (__bf16)x;
        srow[p] = (__bf16)sig;
        ssp += sp; sss += sig;
    }
    __shared__ float sm1[8], sm2[8];
    float w1 = wave_reduce_sum(ssp), w2 = wave_reduce_sum(sss);
    int lane = threadIdx.x & 63, wid = threadIdx.x >> 6;
    if (lane == 0) { sm1[wid] = w1; sm2[wid] = w2; }
    __syncthreads();
    if (threadIdx.x == 0) {
        float a = 0.f, b = 0.f;
#pragma unroll
        for (int i = 0; i < 8; ++i) { a += sm1[i]; b += sm2[i]; }
        spsum[n] = a; ssum[n] = b;
    }
}

// --- gather y at sampled points directly into MFMA-B-fragment order:
//     frag (t,j): lane l holds B[k = t*32 + (l>>4)*8 + jj][m = 16*j + (l&15)]
//       = tgt_masks[m][point_idx[k]],  k < PN gathered index.
//     Also accumulates ysum[m]. Grid: 5 j-subtiles x 49 t-chunks (8 t each),
//     4 waves/block -> 2 t per wave. ---
__global__ __launch_bounds__(256) void gather_y_kernel(
        const float* __restrict__ tgt_masks, const int* __restrict__ point_idx,
        __bf16* __restrict__ Yb, float* __restrict__ ysum) {
    int j = blockIdx.x / 49;
    int tchunk = blockIdx.x % 49;
    int wave = threadIdx.x >> 6, lane = threadIdx.x & 63;
    int colL = lane & 15, quad = lane >> 4;
    int m = 16 * j + colL;                       // always < 80
    const float* yrow = tgt_masks + (size_t)m * PFULL;
    bf16x8* out = (bf16x8*)Yb;
    float acc = 0.f;
#pragma unroll
    for (int u = 0; u < 2; ++u) {
        int t = tchunk * 8 + wave * 2 + u;
        int k0 = t * 32 + quad * 8;
        int idx[8];
        *(int4*)(idx)     = *(const int4*)(point_idx + k0);
        *(int4*)(idx + 4) = *(const int4*)(point_idx + k0 + 4);
        bf16x8 v;
#pragma unroll
        for (int jj = 0; jj < 8; ++jj) {
            float y = yrow[idx[jj]];
            v[jj] = (__bf16)y;
            acc += y;
        }
        out[(size_t)(t * 5 + j) * 64 + lane] = v;
    }
    // reduce the 4 quads holding the same m before the atomic
    acc += __shfl_down(acc, 32, 64);
    acc += __shfl_down(acc, 16, 64);
    if (quad == 0) atomicAdd(&ysum[m], acc);
}

// --- pure-bf16 GEMM: xy = X.Y^T and sy = S.Y^T over K=PN.
//     Per wave: one 16-row n-tile x all 80 m, TPB k-steps.
//     Zero transcendentals; 7 coalesced loads + 10 MFMAs per step. ---
__global__ __launch_bounds__(256) void mfma_gemm_kernel(
        const __bf16* __restrict__ Xb, const __bf16* __restrict__ Sb,
        const __bf16* __restrict__ Yb,
        float* __restrict__ xyacc, float* __restrict__ syacc) {
    int wave = threadIdx.x >> 6, lane = threadIdx.x & 63;
    int nsub = blockIdx.x * 4 + wave;
    int nclamp = nsub < NSUB ? nsub : NSUB - 1;  // clamped waves recompute, skip epilogue
    int n0 = nclamp * 16;
    int colL = lane & 15, quad = lane >> 4;
    int tbase = blockIdx.y * TPB;

    const __bf16* xrow = Xb + (size_t)(n0 + colL) * PN;  // A[m=lane&15]
    const __bf16* srow = Sb + (size_t)(n0 + colL) * PN;
    const bf16x8* Yfrag = (const bf16x8*)Yb;

    f32x4 accX[5], accS[5];
    f32x4 zero = {0.f, 0.f, 0.f, 0.f};
#pragma unroll
    for (int j = 0; j < 5; ++j) { accX[j] = zero; accS[j] = zero; }

    bf16x8 Abuf[2], Sbuf[2], Bbuf[2][5];
    auto load = [&](int i, int b) {
        int t = tbase + i;
        size_t ko = (size_t)t * 32 + quad * 8;
        Abuf[b] = *(const bf16x8*)(xrow + ko);
        Sbuf[b] = *(const bf16x8*)(srow + ko);
        const bf16x8* q = Yfrag + (size_t)(t * 5) * 64 + lane;
#pragma unroll
        for (int j = 0; j < 5; ++j) Bbuf[b][j] = q[(size_t)j * 64];
    };

    load(0, 0);
#pragma unroll
    for (int i = 0; i < TPB; ++i) {
        int b = i & 1;
        if (i + 1 < TPB) load(i + 1, b ^ 1);
#pragma unroll
        for (int j = 0; j < 5; ++j) {
            accX[j] = __builtin_amdgcn_mfma_f32_16x16x32_bf16(Abuf[b], Bbuf[b][j], accX[j], 0, 0, 0);
            accS[j] = __builtin_amdgcn_mfma_f32_16x16x32_bf16(Sbuf[b], Bbuf[b][j], accS[j], 0, 0, 0);
        }
    }

    if (nsub < NSUB) {
        // C/D: n = n0 + quad*4 + reg, m = 16*j + colL  [verified layout]
#pragma unroll
        for (int j = 0; j < 5; ++j)
#pragma unroll
            for (int r = 0; r < 4; ++r) {
                int n = n0 + quad * 4 + r;
                int m = 16 * j + colL;
                atomicAdd(&xyacc[n * M_ROWS + m], accX[j][r]);
                atomicAdd(&syacc[n * M_ROWS + m], accS[j][r]);
            }
    }
}

// --- combine all cost terms ---
__global__ void combine_kernel(const float* __restrict__ logits,
                               const int* __restrict__ tgt_labels,
                               const float* __restrict__ rowmax,
                               const float* __restrict__ rowsum,
                               const float* __restrict__ spsum,
                               const float* __restrict__ ssum,
                               const float* __restrict__ ysum,
                               const float* __restrict__ xyacc,
                               const float* __restrict__ syacc,
                               float* __restrict__ out) {
    int idx = blockIdx.x * blockDim.x + threadIdx.x;
    if (idx >= N_ROWS * M_ROWS) return;
    int n = idx / M_ROWS, m = idx % M_ROWS;
    int tid = tgt_labels[m];
    tid = min(max(tid, 0), K_CLS - 1);
    float p = expf(logits[n * K_CLS + tid] - rowmax[n]) / rowsum[n];
    float cost_class = -p;
    float cost_mask = (spsum[n] - xyacc[idx]) * (1.0f / PN);
    float cost_dice = 1.f - (2.f * syacc[idx] + 1.f) / (ssum[n] + ysum[m] + 1.f);
    out[idx] = 2.f * cost_class + 5.f * cost_mask + 5.f * cost_dice;
}

extern "C" void kernel_launch(void* const* d_in, const int* in_sizes, int n_in,
                              void* d_out, int out_size, void* d_ws, size_t ws_size,
                              hipStream_t stream) {
    const float* pred_logits = (const float*)d_in[0];   // (4,100,134)
    const float* pred_masks  = (const float*)d_in[1];   // (4,100,256,256)
    const int*   tgt_labels  = (const int*)d_in[2];     // (80,)
    const float* tgt_masks   = (const float*)d_in[3];   // (80,256,256)
    const int*   point_idx   = (const int*)d_in[4];     // (12544,)
    float* out = (float*)d_out;                         // (4,100,80)

    char* ws = (char*)d_ws;
    size_t off = 0;
    auto carve = [&](size_t nbytes) {
        char* p = ws + off;
        off += (nbytes + 255) & ~(size_t)255;
        return p;
    };
    // ---- zero-init region (one memset) ----
    float* xyacc = (float*)carve((size_t)N_ROWS * M_ROWS * 4);
    float* syacc = (float*)carve((size_t)N_ROWS * M_ROWS * 4);
    float* ysum  = (float*)carve(M_ROWS * 4);
    size_t zero_bytes = off;
    // ---- no-init region (fully overwritten every launch) ----
    float* spsum  = (float*)carve(N_ROWS * 4);
    float* ssum   = (float*)carve(N_ROWS * 4);
    float* rowmax = (float*)carve(N_ROWS * 4);
    float* rowsum = (float*)carve(N_ROWS * 4);
    __bf16* Xb = (__bf16*)carve((size_t)N_ROWS * PN * 2);   // 10.04 MB
    __bf16* Sb = (__bf16*)carve((size_t)N_ROWS * PN * 2);   // 10.04 MB
    __bf16* Yb = (__bf16*)carve((size_t)TSTEPS * 5 * 1024); //  2.01 MB
    (void)ws_size;

    hipMemsetAsync(xyacc, 0, zero_bytes, stream);
    gather_x_kernel<<<N_ROWS, 512, 0, stream>>>(pred_masks, point_idx, Xb, Sb, spsum, ssum);
    gather_y_kernel<<<5 * 49, 256, 0, stream>>>(tgt_masks, point_idx, Yb, ysum);
    softmax_stats_kernel<<<N_ROWS, 64, 0, stream>>>(pred_logits, rowmax, rowsum);
    dim3 grid((NSUB + 3) / 4, KSPLIT);   // 7 x 56 blocks, 4 waves/block
    mfma_gemm_kernel<<<grid, 256, 0, stream>>>(Xb, Sb, Yb, xyacc, syacc);
    combine_kernel<<<(N_ROWS * M_ROWS + 255) / 256, 256, 0, stream>>>(
        pred_logits, tgt_labels, rowmax, rowsum, spsum, ssum, ysum, xyacc, syacc, out);
}

// Round 5
// 222.563 us; speedup vs baseline: 1.1332x; 1.1332x over previous
//
#include <hip/hip_runtime.h>
#include <math.h>

#define N_ROWS 400      // bs*Q
#define M_ROWS 80       // = 5*16
#define K_CLS  134
#define PN     12544    // = 392*32
#define PFULL  65536    // 256*256
#define NSUB   25       // 400/16 n-subtiles
#define TSTEPS 392      // PN/32 MFMA k-steps
#define KSPLIT 56
#define TPB    7        // TSTEPS/KSPLIT

#define GX_BLOCKS 400
#define GY_BLOCKS 245   // 5 j-subtiles * 49 t-chunks
#define SM_BLOCKS 50    // 400 rows / 8 waves

typedef __attribute__((ext_vector_type(4))) float  f32x4;
typedef __attribute__((ext_vector_type(8))) __bf16 bf16x8;
typedef __attribute__((ext_vector_type(4))) __bf16 bf16x4;

__device__ __forceinline__ float wave_reduce_sum(float v) {
#pragma unroll
    for (int off = 32; off > 0; off >>= 1) v += __shfl_down(v, off, 64);
    return v;
}

// --- single-block: sel = sorted(point_idx) via LDS bitmap + scan;
//     also zeroes the accumulator region (replaces memset dispatch). ---
__global__ __launch_bounds__(1024) void sel_sort_kernel(
        const int* __restrict__ point_idx, int* __restrict__ sel,
        float* __restrict__ zero_region, int zero_n) {
    __shared__ unsigned int flagw[PFULL / 4];   // 64 KB of 0/1 bytes
    __shared__ int wtot[16], wbase[16];
    int tid = threadIdx.x;
    for (int i = tid; i < PFULL / 4; i += 1024) flagw[i] = 0u;
    for (int i = tid; i < zero_n; i += 1024) zero_region[i] = 0.f;
    __syncthreads();
    unsigned char* flag = (unsigned char*)flagw;
    for (int i = tid; i < PN; i += 1024) flag[point_idx[i]] = 1;
    __syncthreads();
    // each thread owns 64 bytes = 16 words
    unsigned int w[16];
    int cnt = 0;
#pragma unroll
    for (int j = 0; j < 16; ++j) {
        w[j] = flagw[tid * 16 + j];
        cnt += (int)((w[j] * 0x01010101u) >> 24);   // bytes are 0/1, sum<=4
    }
    // wave-level inclusive scan of counts
    int lane = tid & 63, wid = tid >> 6;
    int v = cnt;
#pragma unroll
    for (int off = 1; off < 64; off <<= 1) {
        int u = __shfl_up(v, off, 64);
        if (lane >= off) v += u;
    }
    if (lane == 63) wtot[wid] = v;
    __syncthreads();
    if (tid == 0) {
        int run = 0;
#pragma unroll
        for (int i = 0; i < 16; ++i) { wbase[i] = run; run += wtot[i]; }
    }
    __syncthreads();
    int base = wbase[wid] + (v - cnt);              // exclusive prefix
#pragma unroll
    for (int j = 0; j < 16; ++j) {
        unsigned int u = w[j];
        int p0 = tid * 64 + j * 4;
        if (u & 0x01u)       sel[base++] = p0;
        if (u & 0x0100u)     sel[base++] = p0 + 1;
        if (u & 0x010000u)   sel[base++] = p0 + 2;
        if (u & 0x01000000u) sel[base++] = p0 + 3;
    }
}

// --- fused stage1: blocks [0,400) gather x; [400,645) gather y into
//     B-fragment layout; [645,695) softmax stats. All use sorted sel. ---
__global__ __launch_bounds__(512) void stage1_kernel(
        const float* __restrict__ pred_masks, const float* __restrict__ tgt_masks,
        const float* __restrict__ pred_logits, const int* __restrict__ sel,
        __bf16* __restrict__ Xb, __bf16* __restrict__ Sb, __bf16* __restrict__ Yb,
        float* __restrict__ spsum, float* __restrict__ ssum, float* __restrict__ ysum,
        float* __restrict__ rowmax, float* __restrict__ rowsum) {
    __shared__ float smem[128];
    int b = blockIdx.x;
    if (b < GX_BLOCKS) {
        // ---- gather x: one row per block, 4 consecutive sorted points/lane ----
        int n = b;
        const float* row = pred_masks + (size_t)n * PFULL;
        __bf16* xr = Xb + (size_t)n * PN;
        __bf16* sr = Sb + (size_t)n * PN;
        float ssp = 0.f, sss = 0.f;
#pragma unroll
        for (int it = 0; it < 7; ++it) {
            int k0 = it * 2048 + (int)threadIdx.x * 4;
            if (k0 < PN) {
                int4 id = *(const int4*)(sel + k0);
                float xs0 = row[id.x], xs1 = row[id.y], xs2 = row[id.z], xs3 = row[id.w];
                float xs[4] = {xs0, xs1, xs2, xs3};
                bf16x4 vx, vs;
#pragma unroll
                for (int q = 0; q < 4; ++q) {
                    float x  = xs[q];
                    float ax = fabsf(x);
                    float e  = __expf(-ax);
                    float inv = __builtin_amdgcn_rcpf(1.f + e);
                    float sig = (x >= 0.f) ? inv : e * inv;
                    float sp  = fmaxf(x, 0.f) + __logf(1.f + e);
                    vx[q] = (__bf16)x; vs[q] = (__bf16)sig;
                    ssp += sp; sss += sig;
                }
                *(bf16x4*)(xr + k0) = vx;
                *(bf16x4*)(sr + k0) = vs;
            }
        }
        float w1 = wave_reduce_sum(ssp), w2 = wave_reduce_sum(sss);
        int lane = threadIdx.x & 63, wid = threadIdx.x >> 6;
        if (lane == 0) { smem[wid] = w1; smem[8 + wid] = w2; }
        __syncthreads();
        if (threadIdx.x == 0) {
            float a = 0.f, c = 0.f;
#pragma unroll
            for (int i = 0; i < 8; ++i) { a += smem[i]; c += smem[8 + i]; }
            spsum[n] = a; ssum[n] = c;
        }
    } else if (b < GX_BLOCKS + GY_BLOCKS) {
        // ---- gather y into B-frag layout: frag (t,j), lane l holds
        //      B[k = t*32 + (l>>4)*8 + jj][m = 16*j + (l&15)] ----
        int bb = b - GX_BLOCKS;
        int j = bb / 49, tch = bb % 49;
        int wave = threadIdx.x >> 6, lane = threadIdx.x & 63;
        int colL = lane & 15, quad = lane >> 4;
        int m = 16 * j + colL;
        int t = tch * 8 + wave;
        int k0 = t * 32 + quad * 8;
        const float* yrow = tgt_masks + (size_t)m * PFULL;
        int idx[8];
        *(int4*)(idx)     = *(const int4*)(sel + k0);
        *(int4*)(idx + 4) = *(const int4*)(sel + k0 + 4);
        bf16x8 v; float acc = 0.f;
#pragma unroll
        for (int jj = 0; jj < 8; ++jj) {
            float y = yrow[idx[jj]];
            v[jj] = (__bf16)y;
            acc += y;
        }
        ((bf16x8*)Yb)[(size_t)(t * 5 + j) * 64 + lane] = v;
        acc += __shfl_down(acc, 32, 64);
        acc += __shfl_down(acc, 16, 64);
        if (quad == 0) smem[wave * 16 + colL] = acc;
        __syncthreads();
        if (threadIdx.x < 16) {
            float s = 0.f;
#pragma unroll
            for (int wv = 0; wv < 8; ++wv) s += smem[wv * 16 + threadIdx.x];
            atomicAdd(&ysum[16 * j + threadIdx.x], s);
        }
    } else {
        // ---- softmax stats: one row per wave ----
        int bb = b - GX_BLOCKS - GY_BLOCKS;
        int wave = threadIdx.x >> 6, lane = threadIdx.x & 63;
        int n = bb * 8 + wave;                      // < 400
        const float* row = pred_logits + n * K_CLS;
        float mx = -1e30f;
        for (int k = lane; k < K_CLS; k += 64) mx = fmaxf(mx, row[k]);
#pragma unroll
        for (int off = 32; off > 0; off >>= 1) mx = fmaxf(mx, __shfl_down(mx, off, 64));
        mx = __shfl(mx, 0, 64);
        float se = 0.f;
        for (int k = lane; k < K_CLS; k += 64) se += expf(row[k] - mx);
        se = wave_reduce_sum(se);
        if (lane == 0) { rowmax[n] = mx; rowsum[n] = se; }
    }
}

// --- pure-bf16 GEMM: xy = X.Y^T and sy = S.Y^T over K=PN. ---
__global__ __launch_bounds__(256) void mfma_gemm_kernel(
        const __bf16* __restrict__ Xb, const __bf16* __restrict__ Sb,
        const __bf16* __restrict__ Yb,
        float* __restrict__ xyacc, float* __restrict__ syacc) {
    int wave = threadIdx.x >> 6, lane = threadIdx.x & 63;
    int nsub = blockIdx.x * 4 + wave;
    int nclamp = nsub < NSUB ? nsub : NSUB - 1;  // clamped waves recompute, skip epilogue
    int n0 = nclamp * 16;
    int colL = lane & 15, quad = lane >> 4;
    int tbase = blockIdx.y * TPB;

    const __bf16* xrow = Xb + (size_t)(n0 + colL) * PN;  // A[m=lane&15]
    const __bf16* srow = Sb + (size_t)(n0 + colL) * PN;
    const bf16x8* Yfrag = (const bf16x8*)Yb;

    f32x4 accX[5], accS[5];
    f32x4 zero = {0.f, 0.f, 0.f, 0.f};
#pragma unroll
    for (int j = 0; j < 5; ++j) { accX[j] = zero; accS[j] = zero; }

    bf16x8 Abuf[2], Sbuf[2], Bbuf[2][5];
    auto load = [&](int i, int bb) {
        int t = tbase + i;
        size_t ko = (size_t)t * 32 + quad * 8;
        Abuf[bb] = *(const bf16x8*)(xrow + ko);
        Sbuf[bb] = *(const bf16x8*)(srow + ko);
        const bf16x8* q = Yfrag + (size_t)(t * 5) * 64 + lane;
#pragma unroll
        for (int j = 0; j < 5; ++j) Bbuf[bb][j] = q[(size_t)j * 64];
    };

    load(0, 0);
#pragma unroll
    for (int i = 0; i < TPB; ++i) {
        int bb = i & 1;
        if (i + 1 < TPB) load(i + 1, bb ^ 1);
#pragma unroll
        for (int j = 0; j < 5; ++j) {
            accX[j] = __builtin_amdgcn_mfma_f32_16x16x32_bf16(Abuf[bb], Bbuf[bb][j], accX[j], 0, 0, 0);
            accS[j] = __builtin_amdgcn_mfma_f32_16x16x32_bf16(Sbuf[bb], Bbuf[bb][j], accS[j], 0, 0, 0);
        }
    }

    if (nsub < NSUB) {
        // C/D: n = n0 + quad*4 + reg, m = 16*j + colL  [verified layout]
#pragma unroll
        for (int j = 0; j < 5; ++j)
#pragma unroll
            for (int r = 0; r < 4; ++r) {
                int n = n0 + quad * 4 + r;
                int m = 16 * j + colL;
                atomicAdd(&xyacc[n * M_ROWS + m], accX[j][r]);
                atomicAdd(&syacc[n * M_ROWS + m], accS[j][r]);
            }
    }
}

// --- combine all cost terms ---
__global__ void combine_kernel(const float* __restrict__ logits,
                               const int* __restrict__ tgt_labels,
                               const float* __restrict__ rowmax,
                               const float* __restrict__ rowsum,
                               const float* __restrict__ spsum,
                               const float* __restrict__ ssum,
                               const float* __restrict__ ysum,
                               const float* __restrict__ xyacc,
                               const float* __restrict__ syacc,
                               float* __restrict__ out) {
    int idx = blockIdx.x * blockDim.x + threadIdx.x;
    if (idx >= N_ROWS * M_ROWS) return;
    int n = idx / M_ROWS, m = idx % M_ROWS;
    int tid = tgt_labels[m];
    tid = min(max(tid, 0), K_CLS - 1);
    float p = expf(logits[n * K_CLS + tid] - rowmax[n]) / rowsum[n];
    float cost_class = -p;
    float cost_mask = (spsum[n] - xyacc[idx]) * (1.0f / PN);
    float cost_dice = 1.f - (2.f * syacc[idx] + 1.f) / (ssum[n] + ysum[m] + 1.f);
    out[idx] = 2.f * cost_class + 5.f * cost_mask + 5.f * cost_dice;
}

extern "C" void kernel_launch(void* const* d_in, const int* in_sizes, int n_in,
                              void* d_out, int out_size, void* d_ws, size_t ws_size,
                              hipStream_t stream) {
    const float* pred_logits = (const float*)d_in[0];   // (4,100,134)
    const float* pred_masks  = (const float*)d_in[1];   // (4,100,256,256)
    const int*   tgt_labels  = (const int*)d_in[2];     // (80,)
    const float* tgt_masks   = (const float*)d_in[3];   // (80,256,256)
    const int*   point_idx   = (const int*)d_in[4];     // (12544,)
    float* out = (float*)d_out;                         // (4,100,80)

    char* ws = (char*)d_ws;
    size_t off = 0;
    auto carve = [&](size_t nbytes) {
        char* p = ws + off;
        off += (nbytes + 255) & ~(size_t)255;
        return p;
    };
    // ---- zeroed-in-sel_sort region (contiguous) ----
    float* xyacc = (float*)carve((size_t)N_ROWS * M_ROWS * 4);
    float* syacc = (float*)carve((size_t)N_ROWS * M_ROWS * 4);
    float* ysum  = (float*)carve(M_ROWS * 4);
    int zero_n = (int)(off / 4);
    // ---- fully-overwritten region ----
    int*   sel    = (int*)carve(PN * 4);
    float* spsum  = (float*)carve(N_ROWS * 4);
    float* ssum   = (float*)carve(N_ROWS * 4);
    float* rowmax = (float*)carve(N_ROWS * 4);
    float* rowsum = (float*)carve(N_ROWS * 4);
    __bf16* Xb = (__bf16*)carve((size_t)N_ROWS * PN * 2);   // 10.04 MB
    __bf16* Sb = (__bf16*)carve((size_t)N_ROWS * PN * 2);   // 10.04 MB
    __bf16* Yb = (__bf16*)carve((size_t)TSTEPS * 5 * 1024); //  2.01 MB
    (void)ws_size; (void)in_sizes; (void)n_in; (void)out_size;

    sel_sort_kernel<<<1, 1024, 0, stream>>>(point_idx, sel, xyacc, zero_n);
    stage1_kernel<<<GX_BLOCKS + GY_BLOCKS + SM_BLOCKS, 512, 0, stream>>>(
        pred_masks, tgt_masks, pred_logits, sel, Xb, Sb, Yb,
        spsum, ssum, ysum, rowmax, rowsum);
    dim3 grid((NSUB + 3) / 4, KSPLIT);   // 7 x 56 blocks, 4 waves/block
    mfma_gemm_kernel<<<grid, 256, 0, stream>>>(Xb, Sb, Yb, xyacc, syacc);
    combine_kernel<<<(N_ROWS * M_ROWS + 255) / 256, 256, 0, stream>>>(
        pred_logits, tgt_labels, rowmax, rowsum, spsum, ssum, ysum, xyacc, syacc, out);
}

// Round 6
// 217.735 us; speedup vs baseline: 1.1583x; 1.0222x over previous
//
#include <hip/hip_runtime.h>
#include <math.h>

#define N_ROWS 400      // bs*Q
#define M_ROWS 80       // = 5*16
#define K_CLS  134
#define PN     12544    // = 392*32
#define PFULL  65536    // 256*256
#define NSUB   25       // 400/16 n-subtiles
#define TSTEPS 392      // PN/32 MFMA k-steps
#define KSPLIT 98
#define TPB    4        // TSTEPS/KSPLIT

#define GY_BLOCKS 245   // 5 j-subtiles * 49 t-chunks
#define SM_BLOCKS 50    // 400 rows / 8 waves

typedef __attribute__((ext_vector_type(4))) float  f32x4;
typedef __attribute__((ext_vector_type(8))) __bf16 bf16x8;

__device__ __forceinline__ float wave_reduce_sum(float v) {
#pragma unroll
    for (int off = 32; off > 0; off >>= 1) v += __shfl_down(v, off, 64);
    return v;
}

// --- single-block: sel = sorted(point_idx) via LDS bitmap + scan;
//     also zeroes all accumulators (replaces memset dispatch). ---
__global__ __launch_bounds__(1024) void sel_sort_kernel(
        const int* __restrict__ point_idx, int* __restrict__ sel,
        float* __restrict__ zero_region, int zero_n) {
    __shared__ unsigned int flagw[PFULL / 4];   // 64 KB of 0/1 bytes
    __shared__ int wtot[16], wbase[16];
    int tid = threadIdx.x;
    for (int i = tid; i < PFULL / 4; i += 1024) flagw[i] = 0u;
    for (int i = tid; i < zero_n; i += 1024) zero_region[i] = 0.f;
    __syncthreads();
    unsigned char* flag = (unsigned char*)flagw;
    for (int i = tid; i < PN; i += 1024) flag[point_idx[i]] = 1;
    __syncthreads();
    // each thread owns 64 bytes = 16 words
    unsigned int w[16];
    int cnt = 0;
#pragma unroll
    for (int j = 0; j < 16; ++j) {
        w[j] = flagw[tid * 16 + j];
        cnt += (int)((w[j] * 0x01010101u) >> 24);   // bytes are 0/1, sum<=4
    }
    // wave-level inclusive scan of counts
    int lane = tid & 63, wid = tid >> 6;
    int v = cnt;
#pragma unroll
    for (int off = 1; off < 64; off <<= 1) {
        int u = __shfl_up(v, off, 64);
        if (lane >= off) v += u;
    }
    if (lane == 63) wtot[wid] = v;
    __syncthreads();
    if (tid == 0) {
        int run = 0;
#pragma unroll
        for (int i = 0; i < 16; ++i) { wbase[i] = run; run += wtot[i]; }
    }
    __syncthreads();
    int base = wbase[wid] + (v - cnt);              // exclusive prefix
#pragma unroll
    for (int j = 0; j < 16; ++j) {
        unsigned int u = w[j];
        int p0 = tid * 64 + j * 4;
        if (u & 0x01u)       sel[base++] = p0;
        if (u & 0x0100u)     sel[base++] = p0 + 1;
        if (u & 0x010000u)   sel[base++] = p0 + 2;
        if (u & 0x01000000u) sel[base++] = p0 + 3;
    }
}

// --- stage1b: blocks [0,245) gather y into B-fragment layout (+ysum);
//     blocks [245,295) softmax stats. Uses sorted sel. ---
__global__ __launch_bounds__(512) void stage1b_kernel(
        const float* __restrict__ tgt_masks, const float* __restrict__ pred_logits,
        const int* __restrict__ sel, __bf16* __restrict__ Yb,
        float* __restrict__ ysum, float* __restrict__ rowmax, float* __restrict__ rowsum) {
    __shared__ float smem[128];
    int b = blockIdx.x;
    if (b < GY_BLOCKS) {
        // frag (t,j): lane l holds B[k = t*32 + (l>>4)*8 + jj][m = 16*j + (l&15)]
        int j = b / 49, tch = b % 49;
        int wave = threadIdx.x >> 6, lane = threadIdx.x & 63;
        int colL = lane & 15, quad = lane >> 4;
        int m = 16 * j + colL;
        int t = tch * 8 + wave;
        int k0 = t * 32 + quad * 8;
        const float* yrow = tgt_masks + (size_t)m * PFULL;
        int idx[8];
        *(int4*)(idx)     = *(const int4*)(sel + k0);
        *(int4*)(idx + 4) = *(const int4*)(sel + k0 + 4);
        bf16x8 v; float acc = 0.f;
#pragma unroll
        for (int jj = 0; jj < 8; ++jj) {
            float y = yrow[idx[jj]];
            v[jj] = (__bf16)y;
            acc += y;
        }
        ((bf16x8*)Yb)[(size_t)(t * 5 + j) * 64 + lane] = v;
        acc += __shfl_down(acc, 32, 64);
        acc += __shfl_down(acc, 16, 64);
        if (quad == 0) smem[wave * 16 + colL] = acc;
        __syncthreads();
        if (threadIdx.x < 16) {
            float s = 0.f;
#pragma unroll
            for (int wv = 0; wv < 8; ++wv) s += smem[wv * 16 + threadIdx.x];
            atomicAdd(&ysum[16 * j + threadIdx.x], s);
        }
    } else {
        // softmax stats: one row per wave
        int bb = b - GY_BLOCKS;
        int wave = threadIdx.x >> 6, lane = threadIdx.x & 63;
        int n = bb * 8 + wave;                      // < 400
        const float* row = pred_logits + n * K_CLS;
        float mx = -1e30f;
        for (int k = lane; k < K_CLS; k += 64) mx = fmaxf(mx, row[k]);
#pragma unroll
        for (int off = 32; off > 0; off >>= 1) mx = fmaxf(mx, __shfl_down(mx, off, 64));
        mx = __shfl(mx, 0, 64);
        float se = 0.f;
        for (int k = lane; k < K_CLS; k += 64) se += expf(row[k] - mx);
        se = wave_reduce_sum(se);
        if (lane == 0) { rowmax[n] = mx; rowsum[n] = se; }
    }
}

// --- fused gather+GEMM: one wave per (nsub, kchunk). Per t-step each lane
//     gathers 8 x = pred_masks[n0+colL][sel[k]] (sorted sel -> intra-wave line
//     locality, each (row,k-window) owned by exactly one wave), computes
//     sigmoid/softplus in-register, feeds aX/aS MFMA fragments against
//     pre-staged Yb B-fragments. Also split-K row sums of sig/softplus. ---
__global__ __launch_bounds__(256) void gemm_fused_kernel(
        const float* __restrict__ pred_masks, const int* __restrict__ sel,
        const __bf16* __restrict__ Yb,
        float* __restrict__ xyacc, float* __restrict__ syacc,
        float* __restrict__ spsum, float* __restrict__ ssum) {
    int wave = threadIdx.x >> 6, lane = threadIdx.x & 63;
    int flat = blockIdx.x * 4 + wave;
    if (flat >= NSUB * KSPLIT) return;            // no __syncthreads below
    int nsub = flat / KSPLIT, kc = flat % KSPLIT;
    int n0 = nsub * 16;
    int colL = lane & 15, quad = lane >> 4;
    int tbase = kc * TPB;

    const float* row = pred_masks + (size_t)(n0 + colL) * PFULL;  // A row per lane
    const bf16x8* Yfrag = (const bf16x8*)Yb;

    f32x4 accX[5], accS[5];
    f32x4 zero = {0.f, 0.f, 0.f, 0.f};
#pragma unroll
    for (int j = 0; j < 5; ++j) { accX[j] = zero; accS[j] = zero; }
    float sumS = 0.f, sumSP = 0.f;

    float xs[2][8];
    bf16x8 Bbuf[2][5];
    auto load = [&](int i, int b) {
        int t = tbase + i;
        int k0 = t * 32 + quad * 8;
        int idx[8];
        *(int4*)(idx)     = *(const int4*)(sel + k0);
        *(int4*)(idx + 4) = *(const int4*)(sel + k0 + 4);
#pragma unroll
        for (int jj = 0; jj < 8; ++jj) xs[b][jj] = row[idx[jj]];
        const bf16x8* q = Yfrag + (size_t)(t * 5) * 64 + lane;
#pragma unroll
        for (int j = 0; j < 5; ++j) Bbuf[b][j] = q[(size_t)j * 64];
    };
    auto process = [&](int b) {
        bf16x8 aX, aS;
#pragma unroll
        for (int jj = 0; jj < 8; ++jj) {
            float x  = xs[b][jj];
            float ax = fabsf(x);
            float e  = __expf(-ax);
            float inv = __builtin_amdgcn_rcpf(1.f + e);
            float sig = (x >= 0.f) ? inv : e * inv;
            float sp  = fmaxf(x, 0.f) + __logf(1.f + e);
            aX[jj] = (__bf16)x; aS[jj] = (__bf16)sig;
            sumS += sig; sumSP += sp;
        }
#pragma unroll
        for (int j = 0; j < 5; ++j) {
            accX[j] = __builtin_amdgcn_mfma_f32_16x16x32_bf16(aX, Bbuf[b][j], accX[j], 0, 0, 0);
            accS[j] = __builtin_amdgcn_mfma_f32_16x16x32_bf16(aS, Bbuf[b][j], accS[j], 0, 0, 0);
        }
    };

    load(0, 0);
#pragma unroll
    for (int i = 0; i < TPB; ++i) {
        int b = i & 1;
        if (i + 1 < TPB) load(i + 1, b ^ 1);
        process(b);
    }

    // C/D: n = n0 + quad*4 + reg, m = 16*j + colL  [verified layout]
#pragma unroll
    for (int j = 0; j < 5; ++j)
#pragma unroll
        for (int r = 0; r < 4; ++r) {
            int n = n0 + quad * 4 + r;
            int m = 16 * j + colL;
            atomicAdd(&xyacc[n * M_ROWS + m], accX[j][r]);
            atomicAdd(&syacc[n * M_ROWS + m], accS[j][r]);
        }
    // row sums: reduce the 4 quads (same colL = same row), lanes 0..15 commit
    sumS  += __shfl_down(sumS, 32, 64);
    sumS  += __shfl_down(sumS, 16, 64);
    sumSP += __shfl_down(sumSP, 32, 64);
    sumSP += __shfl_down(sumSP, 16, 64);
    if (lane < 16) {
        atomicAdd(&ssum[n0 + lane], sumS);
        atomicAdd(&spsum[n0 + lane], sumSP);
    }
}

// --- combine all cost terms ---
__global__ void combine_kernel(const float* __restrict__ logits,
                               const int* __restrict__ tgt_labels,
                               const float* __restrict__ rowmax,
                               const float* __restrict__ rowsum,
                               const float* __restrict__ spsum,
                               const float* __restrict__ ssum,
                               const float* __restrict__ ysum,
                               const float* __restrict__ xyacc,
                               const float* __restrict__ syacc,
                               float* __restrict__ out) {
    int idx = blockIdx.x * blockDim.x + threadIdx.x;
    if (idx >= N_ROWS * M_ROWS) return;
    int n = idx / M_ROWS, m = idx % M_ROWS;
    int tid = tgt_labels[m];
    tid = min(max(tid, 0), K_CLS - 1);
    float p = expf(logits[n * K_CLS + tid] - rowmax[n]) / rowsum[n];
    float cost_class = -p;
    float cost_mask = (spsum[n] - xyacc[idx]) * (1.0f / PN);
    float cost_dice = 1.f - (2.f * syacc[idx] + 1.f) / (ssum[n] + ysum[m] + 1.f);
    out[idx] = 2.f * cost_class + 5.f * cost_mask + 5.f * cost_dice;
}

extern "C" void kernel_launch(void* const* d_in, const int* in_sizes, int n_in,
                              void* d_out, int out_size, void* d_ws, size_t ws_size,
                              hipStream_t stream) {
    const float* pred_logits = (const float*)d_in[0];   // (4,100,134)
    const float* pred_masks  = (const float*)d_in[1];   // (4,100,256,256)
    const int*   tgt_labels  = (const int*)d_in[2];     // (80,)
    const float* tgt_masks   = (const float*)d_in[3];   // (80,256,256)
    const int*   point_idx   = (const int*)d_in[4];     // (12544,)
    float* out = (float*)d_out;                         // (4,100,80)

    char* ws = (char*)d_ws;
    size_t off = 0;
    auto carve = [&](size_t nbytes) {
        char* p = ws + off;
        off += (nbytes + 255) & ~(size_t)255;
        return p;
    };
    // ---- zeroed-in-sel_sort region (contiguous) ----
    float* xyacc = (float*)carve((size_t)N_ROWS * M_ROWS * 4);
    float* syacc = (float*)carve((size_t)N_ROWS * M_ROWS * 4);
    float* ysum  = (float*)carve(M_ROWS * 4);
    float* spsum = (float*)carve(N_ROWS * 4);
    float* ssum  = (float*)carve(N_ROWS * 4);
    int zero_n = (int)(off / 4);
    // ---- fully-overwritten region ----
    int*   sel    = (int*)carve(PN * 4);
    float* rowmax = (float*)carve(N_ROWS * 4);
    float* rowsum = (float*)carve(N_ROWS * 4);
    __bf16* Yb = (__bf16*)carve((size_t)TSTEPS * 5 * 1024); // 2.01 MB
    (void)ws_size; (void)in_sizes; (void)n_in; (void)out_size;

    sel_sort_kernel<<<1, 1024, 0, stream>>>(point_idx, sel, xyacc, zero_n);
    stage1b_kernel<<<GY_BLOCKS + SM_BLOCKS, 512, 0, stream>>>(
        tgt_masks, pred_logits, sel, Yb, ysum, rowmax, rowsum);
    int nwaves = NSUB * KSPLIT;                    // 2450
    gemm_fused_kernel<<<(nwaves + 3) / 4, 256, 0, stream>>>(
        pred_masks, sel, Yb, xyacc, syacc, spsum, ssum);
    combine_kernel<<<(N_ROWS * M_ROWS + 255) / 256, 256, 0, stream>>>(
        pred_logits, tgt_labels, rowmax, rowsum, spsum, ssum, ysum, xyacc, syacc, out);
}